// Round 7
// baseline (38.503 us; speedup 1.0000x reference)
//
#include <hip/hip_runtime.h>

#define INDIM  128
#define OUTDIM 128
#define GSZ    5
#define BATCH  1024
#define KTOT   1152      // 128 in * 8 w-slots + 128 silu slots
#define APAD   1160      // +8 halfs pad -> LDS row stride 2320B (bank-spread)

typedef _Float16 half_t;
typedef _Float16 half8 __attribute__((ext_vector_type(8)));
typedef float    f32x4 __attribute__((ext_vector_type(4)));

// 8 weight-slot basis values for one x (uniform cubic B-spline, reference knots)
__device__ __forceinline__ half8 basis8(float x, float g0, float g5) {
    const float h  = (g5 - g0) * (1.0f / GSZ);
    const float e0 = ((g0 - h) - h) - h;       // matches reference sequential knot build
    const float xb = (x - e0) * (1.0f / h);
    const float jf = floorf(xb);
    const int   j0 = (int)jf;
    const float u  = xb - jf;
    const float t1 = 1.0f - u;
    const float u2 = u * u, u3 = u2 * u;
    const float c0 = t1 * t1 * t1 * (1.0f / 6.0f);
    const float c1 = fmaf(0.5f, u3, fmaf(-1.0f, u2, 2.0f / 3.0f));
    const float c2 = fmaf(-0.5f, u3, fmaf(0.5f, u2, fmaf(0.5f, u, 1.0f / 6.0f)));
    const float c3 = u3 * (1.0f / 6.0f);
    half8 bs = {0, 0, 0, 0, 0, 0, 0, 0};
#pragma unroll
    for (int k = 0; k < 8; ++k) {
        const int d = k - j0 + 3;              // outside grid -> all-zero (ref-consistent)
        const float v = (d == 0) ? c0 : (d == 1) ? c1 : (d == 2) ? c2 : (d == 3) ? c3 : 0.0f;
        bs[k] = (half_t)v;
    }
    return bs;
}

__device__ __forceinline__ half8 cvt8(float4 a, float4 b, float s) {
    half8 r;
    r[0] = (half_t)(s * a.x); r[1] = (half_t)(s * a.y);
    r[2] = (half_t)(s * a.z); r[3] = (half_t)(s * a.w);
    r[4] = (half_t)(s * b.x); r[5] = (half_t)(s * b.y);
    r[6] = (half_t)(s * b.z); r[7] = (half_t)(s * b.w);
    return r;
}

// bid <  64 : y-block, m-tile of 16 batches, all 128 o
// bid >= 64 : REG-block, one `in`, all 1024 b x 128 o
__global__ __launch_bounds__(256) void k_fused(
    const float* __restrict__ X, const float* __restrict__ G,
    const float* __restrict__ W, const float* __restrict__ Csp,
    const float* __restrict__ Cre,
    float* __restrict__ Y, float* __restrict__ REG)
{
    const int bid = blockIdx.x, t = threadIdx.x;
    const int w = t >> 6, lane = t & 63;
    const int col = lane & 15, quad = lane >> 4;
    const f32x4 zero4 = {0.f, 0.f, 0.f, 0.f};

    if (bid < 64) {
        // ---------------- y: 16x128 output tile ----------------
        __shared__ half_t A[16][APAD];         // [b_local][ktot], 37.1 KB
        const int b0 = bid * 16;
        const int in = t & 127;
        const float g0 = G[in * 6 + 0], g5 = G[in * 6 + 5];
        for (int r = t >> 7; r < 16; r += 2) {
            const float x = X[(b0 + r) * INDIM + in];
            *(half8*)&A[r][in * 8] = basis8(x, g0, g5);
            A[r][1024 + in] = (half_t)(x / (1.0f + __expf(-x)));
        }
        __syncthreads();

#pragma unroll
        for (int nt = 0; nt < 2; ++nt) {
            const int o = (w * 2 + nt) * 16 + col;
            f32x4 acc = zero4;
#pragma unroll 4
            for (int kt = 0; kt < 36; ++kt) {
                const half8 a = *(const half8*)&A[col][kt * 32 + quad * 8];
                half8 bfrag;
                if (kt < 32) {
                    const int s = o * INDIM + (kt * 4 + quad);   // in' = ktot/8
                    const float4 w0 = *(const float4*)&W[s * 8];
                    const float4 w1 = *(const float4*)&W[s * 8 + 4];
                    bfrag = cvt8(w0, w1, Csp[s]);                // csp * W
                } else {
                    const int i0 = (kt - 32) * 32 + quad * 8;
                    const float4 c0 = *(const float4*)&Cre[o * INDIM + i0];
                    const float4 c1 = *(const float4*)&Cre[o * INDIM + i0 + 4];
                    bfrag = cvt8(c0, c1, 1.0f);                  // cre (silu slots)
                }
                acc = __builtin_amdgcn_mfma_f32_16x16x32_f16(a, bfrag, acc, 0, 0, 0);
            }
#pragma unroll
            for (int r = 0; r < 4; ++r)
                Y[(b0 + quad * 4 + r) * OUTDIM + o] = acc[r] * (1.0f / INDIM);
        }
    } else {
        // ---------------- REG: one in, |spl| reduced over b ----------------
        __shared__ half_t Bb[BATCH][8];        // [b][k], 16 KB
        const int in = bid - 64;
        const float g0 = G[in * 6 + 0], g5 = G[in * 6 + 5];
        for (int b = t; b < BATCH; b += 256)
            *(half8*)&Bb[b][0] = basis8(X[b * INDIM + in], g0, g5);
        __syncthreads();

#pragma unroll
        for (int ot = 0; ot < 2; ++ot) {
            const int o0 = (w * 2 + ot) * 16;
            // real k=0..7 live in quad==0 lanes of BOTH A and B (k-map cancels)
            half8 bfrag = {0, 0, 0, 0, 0, 0, 0, 0};
            if (quad == 0) {
                const int s = (o0 + col) * INDIM + in;
                const float4 w0 = *(const float4*)&W[s * 8];
                const float4 w1 = *(const float4*)&W[s * 8 + 4];
                bfrag = cvt8(w0, w1, 1.0f);                      // raw W
            }
            float r0 = 0.f, r1 = 0.f, r2 = 0.f, r3 = 0.f;
#pragma unroll 8
            for (int bt = 0; bt < 64; ++bt) {
                half8 a = {0, 0, 0, 0, 0, 0, 0, 0};
                if (quad == 0)
                    a = *(const half8*)&Bb[bt * 16 + col][0];
                const f32x4 c = __builtin_amdgcn_mfma_f32_16x16x32_f16(a, bfrag, zero4, 0, 0, 0);
                r0 += fabsf(c[0]); r1 += fabsf(c[1]); r2 += fabsf(c[2]); r3 += fabsf(c[3]);
            }
            float sum = (r0 + r1) + (r2 + r3);
            sum += __shfl_xor(sum, 16);
            sum += __shfl_xor(sum, 32);
            if (lane < 16) {
                const int s = (o0 + lane) * INDIM + in;
                const float gg0 = G[s * 6], gg5 = G[s * 6 + 5];
                REG[s] = sum * (1.0f / BATCH) / (gg5 - gg0 + 1e-5f);
            }
        }
    }
}

extern "C" void kernel_launch(void* const* d_in, const int* in_sizes, int n_in,
                              void* d_out, int out_size, void* d_ws, size_t ws_size,
                              hipStream_t stream) {
    const float* X   = (const float*)d_in[0];
    const float* G   = (const float*)d_in[1];
    const float* W   = (const float*)d_in[2];
    const float* Csp = (const float*)d_in[3];
    const float* Cre = (const float*)d_in[4];
    float* Y   = (float*)d_out;                    // (1024,128) unique-owner stores
    float* REG = (float*)d_out + BATCH * OUTDIM;   // (128,128)  unique-owner stores

    k_fused<<<192, 256, 0, stream>>>(X, G, W, Csp, Cre, Y, REG);
}

// Round 8
// 27.219 us; speedup vs baseline: 1.4146x; 1.4146x over previous
//
#include <hip/hip_runtime.h>

#define INDIM  128
#define OUTDIM 128
#define GSZ    5
#define BATCH  1024
#define KTOT   1152      // 128 in * 8 w-slots + 128 silu slots
#define APAD   1160      // pad -> 2320B row stride
#define NY     128       // y-role blocks; REG-role = 1024 blocks

typedef _Float16 half_t;
typedef _Float16 half8 __attribute__((ext_vector_type(8)));
typedef float    f32x4 __attribute__((ext_vector_type(4)));

// 8 weight-slot basis values for one x (uniform cubic B-spline, reference knots)
__device__ __forceinline__ half8 basis8(float x, float g0, float g5) {
    const float h  = (g5 - g0) * (1.0f / GSZ);
    const float e0 = ((g0 - h) - h) - h;       // matches reference sequential knot build
    const float xb = (x - e0) * (1.0f / h);
    const float jf = floorf(xb);
    const int   j0 = (int)jf;
    const float u  = xb - jf;
    const float t1 = 1.0f - u;
    const float u2 = u * u, u3 = u2 * u;
    const float c0 = t1 * t1 * t1 * (1.0f / 6.0f);
    const float c1 = fmaf(0.5f, u3, fmaf(-1.0f, u2, 2.0f / 3.0f));
    const float c2 = fmaf(-0.5f, u3, fmaf(0.5f, u2, fmaf(0.5f, u, 1.0f / 6.0f)));
    const float c3 = u3 * (1.0f / 6.0f);
    half8 bs = {0, 0, 0, 0, 0, 0, 0, 0};
#pragma unroll
    for (int k = 0; k < 8; ++k) {
        const int d = k - j0 + 3;              // outside weight range -> 0 (ref truncation)
        const float v = (d == 0) ? c0 : (d == 1) ? c1 : (d == 2) ? c2 : (d == 3) ? c3 : 0.0f;
        bs[k] = (half_t)v;
    }
    return bs;
}

__device__ __forceinline__ half8 cvt8(float4 a, float4 b, float s) {
    half8 r;
    r[0] = (half_t)(s * a.x); r[1] = (half_t)(s * a.y);
    r[2] = (half_t)(s * a.z); r[3] = (half_t)(s * a.w);
    r[4] = (half_t)(s * b.x); r[5] = (half_t)(s * b.y);
    r[6] = (half_t)(s * b.z); r[7] = (half_t)(s * b.w);
    return r;
}

// bid <  NY  : y-block — 16 batches x 64 o's (wave-per-o-tile, full K)
// bid >= NY  : REG-block — one (in, 16-o slice), all 1024 b (waves split b)
__global__ __launch_bounds__(256) void k_fused(
    const float* __restrict__ X, const float* __restrict__ G,
    const float* __restrict__ W, const float* __restrict__ Csp,
    const float* __restrict__ Cre,
    float* __restrict__ Y, float* __restrict__ REG)
{
    __shared__ __align__(16) unsigned char smem[16 * APAD * 2];   // 37120 B (role-max)
    const int bid = blockIdx.x, t = threadIdx.x;
    const int w = t >> 6, lane = t & 63;
    const int col = lane & 15, quad = lane >> 4;
    const f32x4 zero4 = {0.f, 0.f, 0.f, 0.f};

    if (bid < NY) {
        // ---------------- y: 16m x 64n tile, 4 waves = 4 n-tiles ----------------
        half_t (*A)[APAD] = (half_t (*)[APAD])smem;
        const int m0 = (bid >> 1) * 16;
        const int nh = bid & 1;                 // n half: o in [nh*64, nh*64+64)
        const int in = t & 127;
        const float g0 = G[in * 6 + 0], g5 = G[in * 6 + 5];
        for (int r = t >> 7; r < 16; r += 2) {
            const float x = X[(m0 + r) * INDIM + in];
            *(half8*)&A[r][in * 8] = basis8(x, g0, g5);
            A[r][1024 + in] = (half_t)(x / (1.0f + __expf(-x)));
        }
        __syncthreads();

        const int o = nh * 64 + w * 16 + col;
        f32x4 acc = zero4;
#pragma unroll 6
        for (int kt = 0; kt < 36; ++kt) {
            const half8 a = *(const half8*)&A[col][kt * 32 + quad * 8];
            half8 bfrag;
            if (kt < 32) {
                const int s = o * INDIM + (kt * 4 + quad);   // in' covered by this k-slot
                const float4 w0 = *(const float4*)&W[s * 8];
                const float4 w1 = *(const float4*)&W[s * 8 + 4];
                bfrag = cvt8(w0, w1, Csp[s]);                // csp * W
            } else {
                const int i0 = (kt - 32) * 32 + quad * 8;
                const float4 c0 = *(const float4*)&Cre[o * INDIM + i0];
                const float4 c1 = *(const float4*)&Cre[o * INDIM + i0 + 4];
                bfrag = cvt8(c0, c1, 1.0f);                  // cre (silu slots)
            }
            acc = __builtin_amdgcn_mfma_f32_16x16x32_f16(a, bfrag, acc, 0, 0, 0);
        }
#pragma unroll
        for (int r = 0; r < 4; ++r)
            Y[(m0 + quad * 4 + r) * OUTDIM + o] = acc[r] * (1.0f / INDIM);
    } else {
        // ---------------- REG: one in, 16 o's, |spl| reduced over all b ----------------
        half_t (*Bb)[8] = (half_t (*)[8])smem;               // [1024][8], 16 KB
        float* SH = (float*)(smem + BATCH * 8 * sizeof(half_t));  // [4][16]
        const int rb = bid - NY;
        const int in = rb & 127;
        const int o0 = (rb >> 7) * 16;
        const float g0 = G[in * 6 + 0], g5 = G[in * 6 + 5];
        for (int b = t; b < BATCH; b += 256)
            *(half8*)&Bb[b][0] = basis8(X[b * INDIM + in], g0, g5);
        __syncthreads();

        // real k=0..7 live in quad==0 lanes of BOTH A and B (k-map cancels)
        half8 bfrag = {0, 0, 0, 0, 0, 0, 0, 0};
        if (quad == 0) {
            const int s = (o0 + col) * INDIM + in;
            const float4 w0 = *(const float4*)&W[s * 8];
            const float4 w1 = *(const float4*)&W[s * 8 + 4];
            bfrag = cvt8(w0, w1, 1.0f);                      // raw W
        }
        float r0 = 0.f, r1 = 0.f, r2 = 0.f, r3 = 0.f;
#pragma unroll 4
        for (int bt = w; bt < 64; bt += 4) {                 // waves split the b-tiles
            half8 a = {0, 0, 0, 0, 0, 0, 0, 0};
            if (quad == 0)
                a = *(const half8*)&Bb[bt * 16 + col][0];
            const f32x4 c = __builtin_amdgcn_mfma_f32_16x16x32_f16(a, bfrag, zero4, 0, 0, 0);
            r0 += fabsf(c[0]); r1 += fabsf(c[1]); r2 += fabsf(c[2]); r3 += fabsf(c[3]);
        }
        float sum = (r0 + r1) + (r2 + r3);
        sum += __shfl_xor(sum, 16);
        sum += __shfl_xor(sum, 32);
        if (lane < 16) SH[w * 16 + lane] = sum;              // per-wave partials
        __syncthreads();
        if (t < 16) {
            const int s = (o0 + t) * INDIM + in;
            const float gg0 = G[s * 6], gg5 = G[s * 6 + 5];
            REG[s] = (SH[t] + SH[16 + t] + SH[32 + t] + SH[48 + t])
                     * (1.0f / BATCH) / (gg5 - gg0 + 1e-5f);
        }
    }
}

extern "C" void kernel_launch(void* const* d_in, const int* in_sizes, int n_in,
                              void* d_out, int out_size, void* d_ws, size_t ws_size,
                              hipStream_t stream) {
    const float* X   = (const float*)d_in[0];
    const float* G   = (const float*)d_in[1];
    const float* W   = (const float*)d_in[2];
    const float* Csp = (const float*)d_in[3];
    const float* Cre = (const float*)d_in[4];
    float* Y   = (float*)d_out;                    // (1024,128) unique-owner stores
    float* REG = (float*)d_out + BATCH * OUTDIM;   // (128,128)  unique-owner stores

    k_fused<<<NY + 1024, 256, 0, stream>>>(X, G, W, Csp, Cre, Y, REG);
}